// Round 20
// baseline (108.730 us; speedup 1.0000x reference)
//
#include <hip/hip_runtime.h>
#include <math.h>

#define EPSV 1e-6f
#define NSL  0.2f
#define BB   2
#define NN   2048
#define HH   8
#define TBP  16

typedef short bf16x8 __attribute__((ext_vector_type(8)));
typedef float f32x4  __attribute__((ext_vector_type(4)));

__device__ __forceinline__ unsigned cvt_pk_bf16(float a, float b) {
  unsigned r;
  asm("v_cvt_pk_bf16_f32 %0, %1, %2" : "=v"(r) : "v"(a), "v"(b));
  return r;   // lo16 = bf16(a), hi16 = bf16(b), RNE
}
__device__ __forceinline__ float u2f(unsigned u) {
  union { unsigned u; float f; } v; v.u = u; return v.f;
}
__device__ __forceinline__ float leaky(float a) { return a > 0.f ? a : NSL * a; }

__device__ __forceinline__ void pack8(float4 a, float4 b, uint4& hi, uint4& lo) {
  hi.x = cvt_pk_bf16(a.x, a.y);
  hi.y = cvt_pk_bf16(a.z, a.w);
  hi.z = cvt_pk_bf16(b.x, b.y);
  hi.w = cvt_pk_bf16(b.z, b.w);
  float d0 = a.x - u2f(hi.x << 16), d1 = a.y - u2f(hi.x & 0xffff0000u);
  float d2 = a.z - u2f(hi.y << 16), d3 = a.w - u2f(hi.y & 0xffff0000u);
  float d4 = b.x - u2f(hi.z << 16), d5 = b.y - u2f(hi.z & 0xffff0000u);
  float d6 = b.z - u2f(hi.w << 16), d7 = b.w - u2f(hi.w & 0xffff0000u);
  lo.x = cvt_pk_bf16(d0, d1);
  lo.y = cvt_pk_bf16(d2, d3);
  lo.z = cvt_pk_bf16(d4, d5);
  lo.w = cvt_pk_bf16(d6, d7);
}

// ---------------------------------------------------------------------------
// wconv: f32 weights -> bf16 hi/lo B-fragment tiles (256 tiles).
// ---------------------------------------------------------------------------
__global__ __launch_bounds__(64) void wconv_kernel(
    const float* __restrict__ wq_in, const float* __restrict__ qw1, const float* __restrict__ qw2,
    const float* __restrict__ wkv_in, const float* __restrict__ kw1, const float* __restrict__ kw2,
    const float* __restrict__ w_q, const float* __restrict__ w_k, const float* __restrict__ w_v,
    const float* __restrict__ w_out, const float* __restrict__ ow1, const float* __restrict__ ow2,
    unsigned short* __restrict__ WB)
{
  const int b = blockIdx.x;
  const int lane = threadIdx.x;
  const float* src; int N, toff;
  if      (b < 16)  { src = wq_in;  N = 128; toff = b; }
  else if (b < 32)  { src = qw1;    N = 64;  toff = b - 16; }
  else if (b < 48)  { src = qw2;    N = 128; toff = b - 32; }
  else if (b < 64)  { src = wkv_in; N = 128; toff = b - 48; }
  else if (b < 80)  { src = kw1;    N = 64;  toff = b - 64; }
  else if (b < 96)  { src = kw2;    N = 128; toff = b - 80; }
  else if (b < 128) { src = w_q;    N = 128; toff = b - 96; }
  else if (b < 160) { src = w_k;    N = 128; toff = b - 128; }
  else if (b < 192) { src = w_v;    N = 128; toff = b - 160; }
  else if (b < 224) { src = w_out;  N = 128; toff = b - 192; }
  else if (b < 240) { src = ow1;    N = 64;  toff = b - 224; }
  else              { src = ow2;    N = 128; toff = b - 240; }
  const int NT = N >> 4;
  const int kk = toff / NT, nj = toff % NT;
  const int k0 = kk * 32 + (lane >> 4) * 8;
  const int ch = nj * 16 + (lane & 15);
  float vals[8];
  #pragma unroll
  for (int j = 0; j < 8; ++j) vals[j] = src[(size_t)(k0 + j) * N + ch];
  float4 a = {vals[0], vals[1], vals[2], vals[3]};
  float4 bb = {vals[4], vals[5], vals[6], vals[7]};
  uint4 hi, lo;
  pack8(a, bb, hi, lo);
  unsigned short* dst = WB + (size_t)b * 1024;
  *(uint4*)(dst + lane * 8) = hi;
  *(uint4*)(dst + 512 + lane * 8) = lo;
}

// Workspace fragment layouts (bf16 hi/lo planes):
// QW/KW per (hb, tile16): [hl 2][768]: c0=[lane64][8] @0, c1=[lane<32][8] @512
// VW per (hb, kc32, f):   [hl 2][512]: [lane64][8]

// ---------------------------------------------------------------------------
// pre (MFMA): merged q/kv. 16 tokens / 256 threads. (r16, measured-good)
// ---------------------------------------------------------------------------
__global__ __launch_bounds__(256) void pre_kernel(
    const float* __restrict__ qfts, const float* __restrict__ kvfts,
    const float* __restrict__ qb1, const float* __restrict__ qb2,
    const float* __restrict__ kb1, const float* __restrict__ kb2,
    const unsigned short* __restrict__ WB,
    unsigned short* __restrict__ QW, unsigned short* __restrict__ KW, unsigned short* __restrict__ VW)
{
  const bool is_kv = blockIdx.y != 0;
  const float* x_in = is_kv ? kvfts : qfts;
  const float* b1 = is_kv ? kb1 : qb1;
  const float* b2 = is_kv ? kb2 : qb2;
  unsigned short* FW = is_kv ? KW : QW;
  const float ln_sc = is_kv ? 1.f : 0.25f * 1.44269504088896f;
  const int tb_in = is_kv ? 48 : 0;
  const int tb_w1 = is_kv ? 64 : 16;
  const int tb_w2 = is_kv ? 80 : 32;
  const int tb_p  = is_kv ? 128 : 96;

  const int t0 = blockIdx.x * TBP;
  const int tid = threadIdx.x;
  const int wv = tid >> 6, lane = tid & 63;
  const int col = lane & 15, kg = lane >> 4;
  const int nj0 = wv * 2;
  const int n0 = t0 & (NN - 1), bsel = t0 >> 11;

  __shared__ __align__(16) char smem[50688];
  float* xs       = (float*)smem;
  float* norm_lds = (float*)(smem + 12544);
  float* h_lds    = (float*)(smem + 20992);
  float* f_lds    = (float*)(smem + 25344);
  float* stage    = (float*)smem;

  {
    const float4* src = (const float4*)(x_in + (size_t)t0 * 192);
    #pragma unroll
    for (int i = 0; i < 3; ++i) {
      int idx = tid + i * 256;
      int row = idx / 48, c4 = idx % 48;
      *(float4*)&xs[row * 196 + c4 * 4] = src[idx];
    }
  }
  __syncthreads();

  f32x4 pacc[3][2];
  #pragma unroll
  for (int mf = 0; mf < 3; ++mf)
    #pragma unroll
    for (int njl = 0; njl < 2; ++njl) pacc[mf][njl] = (f32x4){0.f, 0.f, 0.f, 0.f};
  {
    bf16x8 axh[3][2], axl[3][2];
    #pragma unroll
    for (int mf = 0; mf < 3; ++mf)
      #pragma unroll
      for (int kk = 0; kk < 2; ++kk) {
        const float* pa = &xs[col * 196 + mf * 64 + kk * 32 + kg * 8];
        uint4 hi, lo;
        pack8(*(const float4*)pa, *(const float4*)(pa + 4), hi, lo);
        axh[mf][kk] = *(bf16x8*)&hi; axl[mf][kk] = *(bf16x8*)&lo;
      }
    #pragma unroll
    for (int kk = 0; kk < 2; ++kk)
      #pragma unroll
      for (int njl = 0; njl < 2; ++njl) {
        const unsigned short* wb = WB + (size_t)(tb_in + kk * 8 + nj0 + njl) * 1024 + lane * 8;
        bf16x8 bh = *(const bf16x8*)wb;
        bf16x8 bl = *(const bf16x8*)(wb + 512);
        #pragma unroll
        for (int mf = 0; mf < 3; ++mf) {
          pacc[mf][njl] = __builtin_amdgcn_mfma_f32_16x16x32_bf16(axh[mf][kk], bh, pacc[mf][njl], 0, 0, 0);
          pacc[mf][njl] = __builtin_amdgcn_mfma_f32_16x16x32_bf16(axh[mf][kk], bl, pacc[mf][njl], 0, 0, 0);
          pacc[mf][njl] = __builtin_amdgcn_mfma_f32_16x16x32_bf16(axl[mf][kk], bh, pacc[mf][njl], 0, 0, 0);
        }
      }
  }

  f32x4 np4[2]; int zm = 0;
  #pragma unroll
  for (int njl = 0; njl < 2; ++njl) {
    f32x4 ss = pacc[0][njl] * pacc[0][njl] + pacc[1][njl] * pacc[1][njl] + pacc[2][njl] * pacc[2][njl];
    #pragma unroll
    for (int i = 0; i < 4; ++i) {
      float nn = sqrtf(ss[i]);
      if (nn <= EPSV) zm |= 1 << (njl * 4 + i);
      np4[njl][i] = nn + EPSV;
      norm_lds[(kg * 4 + i) * 132 + (nj0 + njl) * 16 + col] = np4[njl][i];
    }
  }
  __syncthreads();

  {
    f32x4 hacc = {0.f, 0.f, 0.f, 0.f};
    #pragma unroll
    for (int kk = 0; kk < 4; ++kk) {
      const float* pa = &norm_lds[col * 132 + kk * 32 + kg * 8];
      uint4 hi, lo;
      pack8(*(const float4*)pa, *(const float4*)(pa + 4), hi, lo);
      bf16x8 ah = *(bf16x8*)&hi, al = *(bf16x8*)&lo;
      const unsigned short* wb = WB + (size_t)(tb_w1 + kk * 4 + wv) * 1024 + lane * 8;
      bf16x8 bh = *(const bf16x8*)wb, bl = *(const bf16x8*)(wb + 512);
      hacc = __builtin_amdgcn_mfma_f32_16x16x32_bf16(ah, bh, hacc, 0, 0, 0);
      hacc = __builtin_amdgcn_mfma_f32_16x16x32_bf16(ah, bl, hacc, 0, 0, 0);
      hacc = __builtin_amdgcn_mfma_f32_16x16x32_bf16(al, bh, hacc, 0, 0, 0);
    }
    float b1v = b1[wv * 16 + col];
    #pragma unroll
    for (int i = 0; i < 4; ++i)
      h_lds[(kg * 4 + i) * 68 + wv * 16 + col] = leaky(hacc[i] + b1v);
  }
  __syncthreads();

  {
    f32x4 bna[2] = {{0.f, 0.f, 0.f, 0.f}, {0.f, 0.f, 0.f, 0.f}};
    #pragma unroll
    for (int kk = 0; kk < 2; ++kk) {
      const float* pa = &h_lds[col * 68 + kk * 32 + kg * 8];
      uint4 hi, lo;
      pack8(*(const float4*)pa, *(const float4*)(pa + 4), hi, lo);
      bf16x8 ah = *(bf16x8*)&hi, al = *(bf16x8*)&lo;
      #pragma unroll
      for (int njl = 0; njl < 2; ++njl) {
        const unsigned short* wb = WB + (size_t)(tb_w2 + kk * 8 + nj0 + njl) * 1024 + lane * 8;
        bf16x8 bh = *(const bf16x8*)wb, bl = *(const bf16x8*)(wb + 512);
        bna[njl] = __builtin_amdgcn_mfma_f32_16x16x32_bf16(ah, bh, bna[njl], 0, 0, 0);
        bna[njl] = __builtin_amdgcn_mfma_f32_16x16x32_bf16(ah, bl, bna[njl], 0, 0, 0);
        bna[njl] = __builtin_amdgcn_mfma_f32_16x16x32_bf16(al, bh, bna[njl], 0, 0, 0);
      }
    }
    #pragma unroll
    for (int njl = 0; njl < 2; ++njl) {
      float b2v = b2[(nj0 + njl) * 16 + col];
      #pragma unroll
      for (int i = 0; i < 4; ++i) {
        float r = (zm >> (njl * 4 + i)) & 1 ? 1.f
                 : (bna[njl][i] + b2v + np4[njl][i]) / np4[njl][i];
        #pragma unroll
        for (int mf = 0; mf < 3; ++mf)
          f_lds[(mf * 16 + kg * 4 + i) * 132 + (nj0 + njl) * 16 + col] = pacc[mf][njl][i] * r;
      }
    }
  }
  __syncthreads();

  f32x4 qacc[3][2], vacc[3][2];
  #pragma unroll
  for (int mf = 0; mf < 3; ++mf)
    #pragma unroll
    for (int njl = 0; njl < 2; ++njl) {
      qacc[mf][njl] = (f32x4){0.f, 0.f, 0.f, 0.f};
      vacc[mf][njl] = (f32x4){0.f, 0.f, 0.f, 0.f};
    }
  #pragma unroll
  for (int kk = 0; kk < 4; ++kk) {
    bf16x8 afh[3], afl[3];
    #pragma unroll
    for (int mf = 0; mf < 3; ++mf) {
      const float* pa = &f_lds[(mf * 16 + col) * 132 + kk * 32 + kg * 8];
      uint4 hi, lo;
      pack8(*(const float4*)pa, *(const float4*)(pa + 4), hi, lo);
      afh[mf] = *(bf16x8*)&hi; afl[mf] = *(bf16x8*)&lo;
    }
    #pragma unroll
    for (int njl = 0; njl < 2; ++njl) {
      const unsigned short* wbq = WB + (size_t)(tb_p + kk * 8 + nj0 + njl) * 1024 + lane * 8;
      bf16x8 qbh = *(const bf16x8*)wbq, qbl = *(const bf16x8*)(wbq + 512);
      #pragma unroll
      for (int mf = 0; mf < 3; ++mf) {
        qacc[mf][njl] = __builtin_amdgcn_mfma_f32_16x16x32_bf16(afh[mf], qbh, qacc[mf][njl], 0, 0, 0);
        qacc[mf][njl] = __builtin_amdgcn_mfma_f32_16x16x32_bf16(afh[mf], qbl, qacc[mf][njl], 0, 0, 0);
        qacc[mf][njl] = __builtin_amdgcn_mfma_f32_16x16x32_bf16(afl[mf], qbh, qacc[mf][njl], 0, 0, 0);
      }
      if (is_kv) {
        const unsigned short* wbv = WB + (size_t)(160 + kk * 8 + nj0 + njl) * 1024 + lane * 8;
        bf16x8 vbh = *(const bf16x8*)wbv, vbl = *(const bf16x8*)(wbv + 512);
        #pragma unroll
        for (int mf = 0; mf < 3; ++mf) {
          vacc[mf][njl] = __builtin_amdgcn_mfma_f32_16x16x32_bf16(afh[mf], vbh, vacc[mf][njl], 0, 0, 0);
          vacc[mf][njl] = __builtin_amdgcn_mfma_f32_16x16x32_bf16(afh[mf], vbl, vacc[mf][njl], 0, 0, 0);
          vacc[mf][njl] = __builtin_amdgcn_mfma_f32_16x16x32_bf16(afl[mf], vbh, vacc[mf][njl], 0, 0, 0);
        }
      }
    }
  }
  __syncthreads();

  #pragma unroll
  for (int njl = 0; njl < 2; ++njl) {
    #pragma unroll
    for (int i = 0; i < 4; ++i) {
      float ss = qacc[0][njl][i] * qacc[0][njl][i]
               + qacc[1][njl][i] * qacc[1][njl][i]
               + qacc[2][njl][i] * qacc[2][njl][i];
      ss += __shfl_xor(ss, 1, 16);
      ss += __shfl_xor(ss, 2, 16);
      ss += __shfl_xor(ss, 4, 16);
      ss += __shfl_xor(ss, 8, 16);
      float inv = ln_sc / (sqrtf(ss * (1.f / 16.f)) + EPSV);
      const int tl = kg * 4 + i;
      #pragma unroll
      for (int mf = 0; mf < 3; ++mf)
        stage[tl * 388 + mf * 128 + (nj0 + njl) * 16 + col] = qacc[mf][njl][i] * inv;
    }
  }
  __syncthreads();

  {
    const int f0 = lane >> 5;
    const int ddb = ((lane >> 4) & 1) * 8;
    const int row = lane & 15;
    #pragma unroll
    for (int h2 = 0; h2 < 2; ++h2) {
      const int hh = wv * 2 + h2;
      const int hbw = hh * BB + bsel;
      const size_t basew = (size_t)(hbw * 128 + (n0 >> 4)) * 1536;
      {
        const float* p0 = stage + row * 388 + f0 * 128 + hh * 16 + ddb;
        uint4 hi, lo;
        pack8(*(const float4*)p0, *(const float4*)(p0 + 4), hi, lo);
        *(uint4*)(FW + basew + lane * 8) = hi;
        *(uint4*)(FW + basew + 768 + lane * 8) = lo;
      }
      if (lane < 32) {
        const float* p1 = stage + row * 388 + 2 * 128 + hh * 16 + ddb;
        uint4 hi, lo;
        pack8(*(const float4*)p1, *(const float4*)(p1 + 4), hi, lo);
        *(uint4*)(FW + basew + 512 + lane * 8) = hi;
        *(uint4*)(FW + basew + 768 + 512 + lane * 8) = lo;
      }
    }
  }

  if (is_kv) {
    __syncthreads();
    #pragma unroll
    for (int njl = 0; njl < 2; ++njl)
      #pragma unroll
      for (int mf = 0; mf < 3; ++mf)
        #pragma unroll
        for (int i = 0; i < 4; ++i)
          stage[mf * 2112 + (kg * 4 + i) * 132 + (nj0 + njl) * 16 + col] = vacc[mf][njl][i];
    __syncthreads();

    const int s0 = (n0 >> 3) & 3;
    if (lane < 32) {
      const int seg = lane;
      const int tlb = (seg >> 4) * 8;
      const int dd = seg & 15;
      #pragma unroll
      for (int h2 = 0; h2 < 2; ++h2) {
        const int hh = wv * 2 + h2;
        const int hbw = hh * BB + bsel;
        #pragma unroll
        for (int f = 0; f < 3; ++f) {
          const size_t vbase = (size_t)((hbw * 64 + (n0 >> 5)) * 3 + f) * 1024;
          float vals[8];
          #pragma unroll
          for (int j = 0; j < 8; ++j)
            vals[j] = stage[f * 2112 + (tlb + j) * 132 + hh * 16 + dd];
          float4 a = {vals[0], vals[1], vals[2], vals[3]};
          float4 b = {vals[4], vals[5], vals[6], vals[7]};
          uint4 hi, lo;
          pack8(a, b, hi, lo);
          *(uint4*)(VW + vbase + (size_t)(s0 * 16 + seg) * 8) = hi;
          *(uint4*)(VW + vbase + 512 + (size_t)(s0 * 16 + seg) * 8) = lo;
        }
      }
    }
  }
}

// ---------------------------------------------------------------------------
// attention: MFMA flash, 4-way K-split, 16 q per wave (qs stripped).
// 1024 blocks = 4/CU = 32 waves/CU; XCD swizzle keeps each hb-pair on one XCD.
// ---------------------------------------------------------------------------
#define THR 10.0f

__global__ __launch_bounds__(512, 8) void attn_kernel(
    const unsigned short* __restrict__ QW, const unsigned short* __restrict__ KW,
    const unsigned short* __restrict__ VW, float* __restrict__ Ob)
{
  const int lane = threadIdx.x & 63;
  const int w = threadIdx.x >> 6;
  const int qt = w & 1;
  const int kq = w >> 1;
  // XCD swizzle for 1024 blocks: XCD k gets hb {2k, 2k+1}.
  const int fid = blockIdx.y * 64 + blockIdx.x;
  const int xcd = fid & 7, slot = fid >> 3;
  const int hb = xcd * 2 + (slot >> 6);
  const int bx = slot & 63;
  const int t = bx * 2 + qt;             // this wave's 16-q tile
  const int q = lane & 15, g = lane >> 4;

  __shared__ unsigned short plds[8][1152];   // [wave][16 q][72] hi bf16
  float* comb = (float*)plds;                 // merge overlay (14.3 KB < 18.4)

  bf16x8 qh0, ql0, qh1, ql1;
  {
    const size_t qbase = (size_t)(hb * 128 + t) * 1536;
    qh0 = *(const bf16x8*)(QW + qbase + lane * 8);
    ql0 = *(const bf16x8*)(QW + qbase + 768 + lane * 8);
    qh1 = (bf16x8){0,0,0,0,0,0,0,0};
    ql1 = (bf16x8){0,0,0,0,0,0,0,0};
    if (lane < 32) {
      qh1 = *(const bf16x8*)(QW + qbase + 512 + lane * 8);
      ql1 = *(const bf16x8*)(QW + qbase + 768 + 512 + lane * 8);
    }
  }

  f32x4 o[3];
  #pragma unroll
  for (int f = 0; f < 3; ++f) o[f] = (f32x4){0.f, 0.f, 0.f, 0.f};
  float m = -INFINITY, l = 0.f;

  for (int T = kq * 8; T < kq * 8 + 8; ++T) {
    f32x4 sc[4];
    __builtin_amdgcn_s_setprio(1);
    #pragma unroll
    for (int st = 0; st < 4; ++st) {
      const size_t kb = (size_t)(hb * 128 + T * 4 + st) * 1536;
      bf16x8 kh0 = *(const bf16x8*)(KW + kb + lane * 8);
      bf16x8 kl0 = *(const bf16x8*)(KW + kb + 768 + lane * 8);
      bf16x8 kh1 = *(const bf16x8*)(KW + kb + 512 + lane * 8);
      bf16x8 kl1 = *(const bf16x8*)(KW + kb + 768 + 512 + lane * 8);
      f32x4 a = {0.f, 0.f, 0.f, 0.f};
      a = __builtin_amdgcn_mfma_f32_16x16x32_bf16(kh0, qh0, a, 0, 0, 0);
      a = __builtin_amdgcn_mfma_f32_16x16x32_bf16(kh0, ql0, a, 0, 0, 0);
      a = __builtin_amdgcn_mfma_f32_16x16x32_bf16(kl0, qh0, a, 0, 0, 0);
      a = __builtin_amdgcn_mfma_f32_16x16x32_bf16(kh1, qh1, a, 0, 0, 0);
      a = __builtin_amdgcn_mfma_f32_16x16x32_bf16(kh1, ql1, a, 0, 0, 0);
      a = __builtin_amdgcn_mfma_f32_16x16x32_bf16(kl1, qh1, a, 0, 0, 0);
      sc[st] = a;
    }
    __builtin_amdgcn_s_setprio(0);

    float tm = sc[0][0];
    #pragma unroll
    for (int st = 0; st < 4; ++st)
      #pragma unroll
      for (int r = 0; r < 4; ++r) tm = fmaxf(tm, sc[st][r]);
    tm = fmaxf(tm, __shfl_xor(tm, 16));
    tm = fmaxf(tm, __shfl_xor(tm, 32));
    if (__any(tm > m + THR)) {
      float mnew = fmaxf(m, tm);
      float scl = __builtin_amdgcn_exp2f(m - mnew);
      l *= scl;
      #pragma unroll
      for (int f = 0; f < 3; ++f) {
        o[f][0] *= scl; o[f][1] *= scl; o[f][2] *= scl; o[f][3] *= scl;
      }
      m = mnew;
    }
    float lp = 0.f;
    #pragma unroll
    for (int st = 0; st < 4; ++st) {
      float p0 = __builtin_amdgcn_exp2f(sc[st][0] - m);
      float p1 = __builtin_amdgcn_exp2f(sc[st][1] - m);
      float p2 = __builtin_amdgcn_exp2f(sc[st][2] - m);
      float p3 = __builtin_amdgcn_exp2f(sc[st][3] - m);
      lp += (p0 + p1) + (p2 + p3);
      uint2 uh = {cvt_pk_bf16(p0, p1), cvt_pk_bf16(p2, p3)};
      *(uint2*)&plds[w][q * 72 + st * 16 + g * 4] = uh;
    }
    lp += __shfl_xor(lp, 16);
    lp += __shfl_xor(lp, 32);
    l += lp;

    asm volatile("s_waitcnt lgkmcnt(0)" ::: "memory");

    __builtin_amdgcn_s_setprio(1);
    #pragma unroll
    for (int c = 0; c < 2; ++c) {
      const int kc = T * 2 + c;
      bf16x8 pb = *(const bf16x8*)&plds[w][q * 72 + c * 32 + g * 8];
      #pragma unroll
      for (int f = 0; f < 3; ++f) {
        const size_t vb = (size_t)((hb * 64 + kc) * 3 + f) * 1024;
        bf16x8 vh = *(const bf16x8*)(VW + vb + lane * 8);
        bf16x8 vl = *(const bf16x8*)(VW + vb + 512 + lane * 8);
        o[f] = __builtin_amdgcn_mfma_f32_16x16x32_bf16(vh, pb, o[f], 0, 0, 0);
        o[f] = __builtin_amdgcn_mfma_f32_16x16x32_bf16(vl, pb, o[f], 0, 0, 0);
      }
    }
    __builtin_amdgcn_s_setprio(0);
  }

  // merge the 4 key-quarters (tree), comb overlays plds
  #define SLOT(qt_, r_) (comb + (((qt_) * 2 + (r_)) * 64 + lane) * 14)
  __syncthreads();
  if (kq & 1) {
    float* cb = SLOT(qt, kq >> 1);
    #pragma unroll
    for (int f = 0; f < 3; ++f)
      #pragma unroll
      for (int r = 0; r < 4; ++r) cb[f * 4 + r] = o[f][r];
    cb[12] = m; cb[13] = l;
  }
  __syncthreads();
  if (!(kq & 1)) {
    const float* cb = SLOT(qt, kq >> 1);
    float m1 = cb[12], l1 = cb[13];
    float mn = fmaxf(m, m1);
    float s0 = __builtin_amdgcn_exp2f(m - mn);
    float s1 = __builtin_amdgcn_exp2f(m1 - mn);
    l = l * s0 + l1 * s1;
    #pragma unroll
    for (int f = 0; f < 3; ++f)
      #pragma unroll
      for (int r = 0; r < 4; ++r)
        o[f][r] = o[f][r] * s0 + cb[f * 4 + r] * s1;
    m = mn;
  }
  __syncthreads();
  if (kq == 2) {
    float* cb = SLOT(qt, 1);
    #pragma unroll
    for (int f = 0; f < 3; ++f)
      #pragma unroll
      for (int r = 0; r < 4; ++r) cb[f * 4 + r] = o[f][r];
    cb[12] = m; cb[13] = l;
  }
  __syncthreads();
  if (kq == 0) {
    const float* cb = SLOT(qt, 1);
    float m1 = cb[12], l1 = cb[13];
    float mn = fmaxf(m, m1);
    float s0 = __builtin_amdgcn_exp2f(m - mn);
    float s1 = __builtin_amdgcn_exp2f(m1 - mn);
    float invl = 1.f / (l * s0 + l1 * s1);
    const int h_ = hb >> 1, b_ = hb & 1;
    const int n = t * 16 + q;
    #pragma unroll
    for (int f = 0; f < 3; ++f) {
      float4 st4 = {(o[f][0] * s0 + cb[f * 4 + 0] * s1) * invl,
                    (o[f][1] * s0 + cb[f * 4 + 1] * s1) * invl,
                    (o[f][2] * s0 + cb[f * 4 + 2] * s1) * invl,
                    (o[f][3] * s0 + cb[f * 4 + 3] * s1) * invl};
      *(float4*)&Ob[(((size_t)(b_ * NN + n)) * 3 + f) * 128 + h_ * 16 + g * 4] = st4;
    }
  }
  #undef SLOT
}

// ---------------------------------------------------------------------------
// out (MFMA): ev_nonlin(resi @ w_out). 16 tokens / 256 threads. (r17 good)
// ---------------------------------------------------------------------------
__global__ __launch_bounds__(256) void out_kernel(
    const float* __restrict__ Ob,
    const float* __restrict__ b1, const float* __restrict__ b2,
    const unsigned short* __restrict__ WB,
    float* __restrict__ out)
{
  const int t0 = blockIdx.x * TBP;
  const int tid = threadIdx.x;
  const int wv = tid >> 6, lane = tid & 63;
  const int col = lane & 15, kg = lane >> 4;
  const int nj0 = wv * 2;

  __shared__ __align__(16) char smem[38144];
  float* rs_lds   = (float*)smem;
  float* norm_lds = (float*)(smem + 25344);
  float* h_lds    = (float*)(smem + 33792);
  float* stage    = (float*)smem;

  {
    const float4* src = (const float4*)(Ob + (size_t)t0 * 384);
    #pragma unroll
    for (int i = 0; i < 6; ++i) {
      int idx = tid + i * 256;
      int tok = idx / 96, rem = idx % 96;
      int f = rem / 32, c4 = rem % 32;
      *(float4*)&rs_lds[f * 2112 + tok * 132 + c4 * 4] = src[idx];
    }
  }
  __syncthreads();

  f32x4 pacc[3][2];
  #pragma unroll
  for (int mf = 0; mf < 3; ++mf)
    #pragma unroll
    for (int njl = 0; njl < 2; ++njl) pacc[mf][njl] = (f32x4){0.f, 0.f, 0.f, 0.f};
  #pragma unroll
  for (int kk = 0; kk < 4; ++kk) {
    bf16x8 ah[3], al[3];
    #pragma unroll
    for (int mf = 0; mf < 3; ++mf) {
      const float* pa = &rs_lds[mf * 2112 + col * 132 + kk * 32 + kg * 8];
      uint4 hi, lo;
      pack8(*(const float4*)pa, *(const float4*)(pa + 4), hi, lo);
      ah[mf] = *(bf16x8*)&hi; al[mf] = *(bf16x8*)&lo;
    }
    #pragma unroll
    for (int njl = 0; njl < 2; ++njl) {
      const unsigned short* wb = WB + (size_t)(192 + kk * 8 + nj0 + njl) * 1024 + lane * 8;
      bf16x8 bh = *(const bf16x8*)wb, bl = *(const bf16x8*)(wb + 512);
      #pragma unroll
      for (int mf = 0; mf < 3; ++mf) {
        pacc[mf][njl] = __builtin_amdgcn_mfma_f32_16x16x32_bf16(ah[mf], bh, pacc[mf][njl], 0, 0, 0);
        pacc[mf][njl] = __builtin_amdgcn_mfma_f32_16x16x32_bf16(ah[mf], bl, pacc[mf][njl], 0, 0, 0);
        pacc[mf][njl] = __builtin_amdgcn_mfma_f32_16x16x32_bf16(al[mf], bh, pacc[mf][njl], 0, 0, 0);
      }
    }
  }

  f32x4 np4[2]; int zm = 0;
  #pragma unroll
  for (int njl = 0; njl < 2; ++njl) {
    f32x4 ss = pacc[0][njl] * pacc[0][njl] + pacc[1][njl] * pacc[1][njl] + pacc[2][njl] * pacc[2][njl];
    #pragma unroll
    for (int i = 0; i < 4; ++i) {
      float nn = sqrtf(ss[i]);
      if (nn <= EPSV) zm |= 1 << (njl * 4 + i);
      np4[njl][i] = nn + EPSV;
      norm_lds[(kg * 4 + i) * 132 + (nj0 + njl) * 16 + col] = np4[njl][i];
    }
  }
  __syncthreads();

  {
    f32x4 hacc = {0.f, 0.f, 0.f, 0.f};
    #pragma unroll
    for (int kk = 0; kk < 4; ++kk) {
      const float* pa = &norm_lds[col * 132 + kk * 32 + kg * 8];
      uint4 hi, lo;
      pack8(*(const float4*)pa, *(const float4*)(pa + 4), hi, lo);
      bf16x8 ah = *(bf16x8*)&hi, al = *(bf16x8*)&lo;
      const unsigned short* wb = WB + (size_t)(224 + kk * 4 + wv) * 1024 + lane * 8;
      bf16x8 bh = *(const bf16x8*)wb, bl = *(const bf16x8*)(wb + 512);
      hacc = __builtin_amdgcn_mfma_f32_16x16x32_bf16(ah, bh, hacc, 0, 0, 0);
      hacc = __builtin_amdgcn_mfma_f32_16x16x32_bf16(ah, bl, hacc, 0, 0, 0);
      hacc = __builtin_amdgcn_mfma_f32_16x16x32_bf16(al, bh, hacc, 0, 0, 0);
    }
    float b1v = b1[wv * 16 + col];
    #pragma unroll
    for (int i = 0; i < 4; ++i)
      h_lds[(kg * 4 + i) * 68 + wv * 16 + col] = leaky(hacc[i] + b1v);
  }
  __syncthreads();

  {
    f32x4 bna[2] = {{0.f, 0.f, 0.f, 0.f}, {0.f, 0.f, 0.f, 0.f}};
    #pragma unroll
    for (int kk = 0; kk < 2; ++kk) {
      const float* pa = &h_lds[col * 68 + kk * 32 + kg * 8];
      uint4 hi, lo;
      pack8(*(const float4*)pa, *(const float4*)(pa + 4), hi, lo);
      bf16x8 ah = *(bf16x8*)&hi, al = *(bf16x8*)&lo;
      #pragma unroll
      for (int njl = 0; njl < 2; ++njl) {
        const unsigned short* wb = WB + (size_t)(240 + kk * 8 + nj0 + njl) * 1024 + lane * 8;
        bf16x8 bh = *(const bf16x8*)wb, bl = *(const bf16x8*)(wb + 512);
        bna[njl] = __builtin_amdgcn_mfma_f32_16x16x32_bf16(ah, bh, bna[njl], 0, 0, 0);
        bna[njl] = __builtin_amdgcn_mfma_f32_16x16x32_bf16(ah, bl, bna[njl], 0, 0, 0);
        bna[njl] = __builtin_amdgcn_mfma_f32_16x16x32_bf16(al, bh, bna[njl], 0, 0, 0);
      }
    }
    __syncthreads();
    #pragma unroll
    for (int njl = 0; njl < 2; ++njl) {
      float b2v = b2[(nj0 + njl) * 16 + col];
      #pragma unroll
      for (int i = 0; i < 4; ++i) {
        float r = (zm >> (njl * 4 + i)) & 1 ? 1.f
                 : (bna[njl][i] + b2v + np4[njl][i]) / np4[njl][i];
        #pragma unroll
        for (int mf = 0; mf < 3; ++mf)
          stage[(kg * 4 + i) * 388 + mf * 128 + (nj0 + njl) * 16 + col] = pacc[mf][njl][i] * r;
      }
    }
  }
  __syncthreads();

  {
    float4* dst = (float4*)(out + (size_t)t0 * 384);
    #pragma unroll
    for (int i = 0; i < 6; ++i) {
      int idx = tid + i * 256;
      int tok = idx / 96, rem = idx % 96;
      dst[idx] = *(const float4*)&stage[tok * 388 + rem * 4];
    }
  }
}

// ---------------------------------------------------------------------------
extern "C" void kernel_launch(void* const* d_in, const int* in_sizes, int n_in,
                              void* d_out, int out_size, void* d_ws, size_t ws_size,
                              hipStream_t stream) {
  const float* qfts   = (const float*)d_in[0];
  const float* kvfts  = (const float*)d_in[1];
  const float* w_q_in = (const float*)d_in[2];
  const float* q_w1   = (const float*)d_in[3];
  const float* q_b1   = (const float*)d_in[4];
  const float* q_w2   = (const float*)d_in[5];
  const float* q_b2   = (const float*)d_in[6];
  const float* w_kv_in= (const float*)d_in[7];
  const float* kv_w1  = (const float*)d_in[8];
  const float* kv_b1  = (const float*)d_in[9];
  const float* kv_w2  = (const float*)d_in[10];
  const float* kv_b2  = (const float*)d_in[11];
  const float* w_q    = (const float*)d_in[12];
  const float* w_k    = (const float*)d_in[13];
  const float* w_v    = (const float*)d_in[14];
  const float* w_out  = (const float*)d_in[15];
  const float* o_w1   = (const float*)d_in[16];
  const float* o_b1   = (const float*)d_in[17];
  const float* o_w2   = (const float*)d_in[18];
  const float* o_b2   = (const float*)d_in[19];

  unsigned short* QW = (unsigned short*)d_ws;
  unsigned short* KW = QW + 3145728;
  unsigned short* VW = KW + 3145728;
  float* Obuf = (float*)(VW + 3145728);
  unsigned short* WB = (unsigned short*)(Obuf + 1572864);

  wconv_kernel<<<256, 64, 0, stream>>>(w_q_in, q_w1, q_w2, w_kv_in, kv_w1, kv_w2,
                                       w_q, w_k, w_v, w_out, o_w1, o_w2, WB);
  dim3 pg(BB * NN / TBP, 2);
  pre_kernel<<<pg, 256, 0, stream>>>(qfts, kvfts, q_b1, q_b2, kv_b1, kv_b2,
                                     WB, QW, KW, VW);
  dim3 ag(64, 16);
  attn_kernel<<<ag, 512, 0, stream>>>(QW, KW, VW, Obuf);
  out_kernel<<<BB * NN / TBP, 256, 0, stream>>>(Obuf, o_b1, o_b2, WB, (float*)d_out);
}

// Round 21
// 80.840 us; speedup vs baseline: 1.3450x; 1.3450x over previous
//
#include <hip/hip_runtime.h>
#include <math.h>

#define EPSV 1e-6f
#define NSL  0.2f
#define BB   2
#define NN   2048
#define HH   8
#define TBP  16

typedef short bf16x8 __attribute__((ext_vector_type(8)));
typedef float f32x4  __attribute__((ext_vector_type(4)));

__device__ __forceinline__ unsigned cvt_pk_bf16(float a, float b) {
  unsigned r;
  asm("v_cvt_pk_bf16_f32 %0, %1, %2" : "=v"(r) : "v"(a), "v"(b));
  return r;   // lo16 = bf16(a), hi16 = bf16(b), RNE
}
__device__ __forceinline__ float u2f(unsigned u) {
  union { unsigned u; float f; } v; v.u = u; return v.f;
}
__device__ __forceinline__ float leaky(float a) { return a > 0.f ? a : NSL * a; }

__device__ __forceinline__ void pack8(float4 a, float4 b, uint4& hi, uint4& lo) {
  hi.x = cvt_pk_bf16(a.x, a.y);
  hi.y = cvt_pk_bf16(a.z, a.w);
  hi.z = cvt_pk_bf16(b.x, b.y);
  hi.w = cvt_pk_bf16(b.z, b.w);
  float d0 = a.x - u2f(hi.x << 16), d1 = a.y - u2f(hi.x & 0xffff0000u);
  float d2 = a.z - u2f(hi.y << 16), d3 = a.w - u2f(hi.y & 0xffff0000u);
  float d4 = b.x - u2f(hi.z << 16), d5 = b.y - u2f(hi.z & 0xffff0000u);
  float d6 = b.z - u2f(hi.w << 16), d7 = b.w - u2f(hi.w & 0xffff0000u);
  lo.x = cvt_pk_bf16(d0, d1);
  lo.y = cvt_pk_bf16(d2, d3);
  lo.z = cvt_pk_bf16(d4, d5);
  lo.w = cvt_pk_bf16(d6, d7);
}

// ---------------------------------------------------------------------------
// wconv: f32 weights -> bf16 hi/lo B-fragment tiles (256 tiles).
// ---------------------------------------------------------------------------
__global__ __launch_bounds__(64) void wconv_kernel(
    const float* __restrict__ wq_in, const float* __restrict__ qw1, const float* __restrict__ qw2,
    const float* __restrict__ wkv_in, const float* __restrict__ kw1, const float* __restrict__ kw2,
    const float* __restrict__ w_q, const float* __restrict__ w_k, const float* __restrict__ w_v,
    const float* __restrict__ w_out, const float* __restrict__ ow1, const float* __restrict__ ow2,
    unsigned short* __restrict__ WB)
{
  const int b = blockIdx.x;
  const int lane = threadIdx.x;
  const float* src; int N, toff;
  if      (b < 16)  { src = wq_in;  N = 128; toff = b; }
  else if (b < 32)  { src = qw1;    N = 64;  toff = b - 16; }
  else if (b < 48)  { src = qw2;    N = 128; toff = b - 32; }
  else if (b < 64)  { src = wkv_in; N = 128; toff = b - 48; }
  else if (b < 80)  { src = kw1;    N = 64;  toff = b - 64; }
  else if (b < 96)  { src = kw2;    N = 128; toff = b - 80; }
  else if (b < 128) { src = w_q;    N = 128; toff = b - 96; }
  else if (b < 160) { src = w_k;    N = 128; toff = b - 128; }
  else if (b < 192) { src = w_v;    N = 128; toff = b - 160; }
  else if (b < 224) { src = w_out;  N = 128; toff = b - 192; }
  else if (b < 240) { src = ow1;    N = 64;  toff = b - 224; }
  else              { src = ow2;    N = 128; toff = b - 240; }
  const int NT = N >> 4;
  const int kk = toff / NT, nj = toff % NT;
  const int k0 = kk * 32 + (lane >> 4) * 8;
  const int ch = nj * 16 + (lane & 15);
  float vals[8];
  #pragma unroll
  for (int j = 0; j < 8; ++j) vals[j] = src[(size_t)(k0 + j) * N + ch];
  float4 a = {vals[0], vals[1], vals[2], vals[3]};
  float4 bb = {vals[4], vals[5], vals[6], vals[7]};
  uint4 hi, lo;
  pack8(a, bb, hi, lo);
  unsigned short* dst = WB + (size_t)b * 1024;
  *(uint4*)(dst + lane * 8) = hi;
  *(uint4*)(dst + 512 + lane * 8) = lo;
}

// Workspace fragment layouts (bf16 hi/lo planes):
// QW/KW per (hb, tile16): [hl 2][768]: c0=[lane64][8] @0, c1=[lane<32][8] @512
// VW per (hb, kc32, f):   [hl 2][512]: [lane64][8]

// ---------------------------------------------------------------------------
// pre (MFMA): merged q/kv. 16 tokens / 256 threads. (r16, measured-good)
// ---------------------------------------------------------------------------
__global__ __launch_bounds__(256) void pre_kernel(
    const float* __restrict__ qfts, const float* __restrict__ kvfts,
    const float* __restrict__ qb1, const float* __restrict__ qb2,
    const float* __restrict__ kb1, const float* __restrict__ kb2,
    const unsigned short* __restrict__ WB,
    unsigned short* __restrict__ QW, unsigned short* __restrict__ KW, unsigned short* __restrict__ VW)
{
  const bool is_kv = blockIdx.y != 0;
  const float* x_in = is_kv ? kvfts : qfts;
  const float* b1 = is_kv ? kb1 : qb1;
  const float* b2 = is_kv ? kb2 : qb2;
  unsigned short* FW = is_kv ? KW : QW;
  const float ln_sc = is_kv ? 1.f : 0.25f * 1.44269504088896f;
  const int tb_in = is_kv ? 48 : 0;
  const int tb_w1 = is_kv ? 64 : 16;
  const int tb_w2 = is_kv ? 80 : 32;
  const int tb_p  = is_kv ? 128 : 96;

  const int t0 = blockIdx.x * TBP;
  const int tid = threadIdx.x;
  const int wv = tid >> 6, lane = tid & 63;
  const int col = lane & 15, kg = lane >> 4;
  const int nj0 = wv * 2;
  const int n0 = t0 & (NN - 1), bsel = t0 >> 11;

  __shared__ __align__(16) char smem[50688];
  float* xs       = (float*)smem;
  float* norm_lds = (float*)(smem + 12544);
  float* h_lds    = (float*)(smem + 20992);
  float* f_lds    = (float*)(smem + 25344);
  float* stage    = (float*)smem;

  {
    const float4* src = (const float4*)(x_in + (size_t)t0 * 192);
    #pragma unroll
    for (int i = 0; i < 3; ++i) {
      int idx = tid + i * 256;
      int row = idx / 48, c4 = idx % 48;
      *(float4*)&xs[row * 196 + c4 * 4] = src[idx];
    }
  }
  __syncthreads();

  f32x4 pacc[3][2];
  #pragma unroll
  for (int mf = 0; mf < 3; ++mf)
    #pragma unroll
    for (int njl = 0; njl < 2; ++njl) pacc[mf][njl] = (f32x4){0.f, 0.f, 0.f, 0.f};
  {
    bf16x8 axh[3][2], axl[3][2];
    #pragma unroll
    for (int mf = 0; mf < 3; ++mf)
      #pragma unroll
      for (int kk = 0; kk < 2; ++kk) {
        const float* pa = &xs[col * 196 + mf * 64 + kk * 32 + kg * 8];
        uint4 hi, lo;
        pack8(*(const float4*)pa, *(const float4*)(pa + 4), hi, lo);
        axh[mf][kk] = *(bf16x8*)&hi; axl[mf][kk] = *(bf16x8*)&lo;
      }
    #pragma unroll
    for (int kk = 0; kk < 2; ++kk)
      #pragma unroll
      for (int njl = 0; njl < 2; ++njl) {
        const unsigned short* wb = WB + (size_t)(tb_in + kk * 8 + nj0 + njl) * 1024 + lane * 8;
        bf16x8 bh = *(const bf16x8*)wb;
        bf16x8 bl = *(const bf16x8*)(wb + 512);
        #pragma unroll
        for (int mf = 0; mf < 3; ++mf) {
          pacc[mf][njl] = __builtin_amdgcn_mfma_f32_16x16x32_bf16(axh[mf][kk], bh, pacc[mf][njl], 0, 0, 0);
          pacc[mf][njl] = __builtin_amdgcn_mfma_f32_16x16x32_bf16(axh[mf][kk], bl, pacc[mf][njl], 0, 0, 0);
          pacc[mf][njl] = __builtin_amdgcn_mfma_f32_16x16x32_bf16(axl[mf][kk], bh, pacc[mf][njl], 0, 0, 0);
        }
      }
  }

  f32x4 np4[2]; int zm = 0;
  #pragma unroll
  for (int njl = 0; njl < 2; ++njl) {
    f32x4 ss = pacc[0][njl] * pacc[0][njl] + pacc[1][njl] * pacc[1][njl] + pacc[2][njl] * pacc[2][njl];
    #pragma unroll
    for (int i = 0; i < 4; ++i) {
      float nn = sqrtf(ss[i]);
      if (nn <= EPSV) zm |= 1 << (njl * 4 + i);
      np4[njl][i] = nn + EPSV;
      norm_lds[(kg * 4 + i) * 132 + (nj0 + njl) * 16 + col] = np4[njl][i];
    }
  }
  __syncthreads();

  {
    f32x4 hacc = {0.f, 0.f, 0.f, 0.f};
    #pragma unroll
    for (int kk = 0; kk < 4; ++kk) {
      const float* pa = &norm_lds[col * 132 + kk * 32 + kg * 8];
      uint4 hi, lo;
      pack8(*(const float4*)pa, *(const float4*)(pa + 4), hi, lo);
      bf16x8 ah = *(bf16x8*)&hi, al = *(bf16x8*)&lo;
      const unsigned short* wb = WB + (size_t)(tb_w1 + kk * 4 + wv) * 1024 + lane * 8;
      bf16x8 bh = *(const bf16x8*)wb, bl = *(const bf16x8*)(wb + 512);
      hacc = __builtin_amdgcn_mfma_f32_16x16x32_bf16(ah, bh, hacc, 0, 0, 0);
      hacc = __builtin_amdgcn_mfma_f32_16x16x32_bf16(ah, bl, hacc, 0, 0, 0);
      hacc = __builtin_amdgcn_mfma_f32_16x16x32_bf16(al, bh, hacc, 0, 0, 0);
    }
    float b1v = b1[wv * 16 + col];
    #pragma unroll
    for (int i = 0; i < 4; ++i)
      h_lds[(kg * 4 + i) * 68 + wv * 16 + col] = leaky(hacc[i] + b1v);
  }
  __syncthreads();

  {
    f32x4 bna[2] = {{0.f, 0.f, 0.f, 0.f}, {0.f, 0.f, 0.f, 0.f}};
    #pragma unroll
    for (int kk = 0; kk < 2; ++kk) {
      const float* pa = &h_lds[col * 68 + kk * 32 + kg * 8];
      uint4 hi, lo;
      pack8(*(const float4*)pa, *(const float4*)(pa + 4), hi, lo);
      bf16x8 ah = *(bf16x8*)&hi, al = *(bf16x8*)&lo;
      #pragma unroll
      for (int njl = 0; njl < 2; ++njl) {
        const unsigned short* wb = WB + (size_t)(tb_w2 + kk * 8 + nj0 + njl) * 1024 + lane * 8;
        bf16x8 bh = *(const bf16x8*)wb, bl = *(const bf16x8*)(wb + 512);
        bna[njl] = __builtin_amdgcn_mfma_f32_16x16x32_bf16(ah, bh, bna[njl], 0, 0, 0);
        bna[njl] = __builtin_amdgcn_mfma_f32_16x16x32_bf16(ah, bl, bna[njl], 0, 0, 0);
        bna[njl] = __builtin_amdgcn_mfma_f32_16x16x32_bf16(al, bh, bna[njl], 0, 0, 0);
      }
    }
    #pragma unroll
    for (int njl = 0; njl < 2; ++njl) {
      float b2v = b2[(nj0 + njl) * 16 + col];
      #pragma unroll
      for (int i = 0; i < 4; ++i) {
        float r = (zm >> (njl * 4 + i)) & 1 ? 1.f
                 : (bna[njl][i] + b2v + np4[njl][i]) / np4[njl][i];
        #pragma unroll
        for (int mf = 0; mf < 3; ++mf)
          f_lds[(mf * 16 + kg * 4 + i) * 132 + (nj0 + njl) * 16 + col] = pacc[mf][njl][i] * r;
      }
    }
  }
  __syncthreads();

  f32x4 qacc[3][2], vacc[3][2];
  #pragma unroll
  for (int mf = 0; mf < 3; ++mf)
    #pragma unroll
    for (int njl = 0; njl < 2; ++njl) {
      qacc[mf][njl] = (f32x4){0.f, 0.f, 0.f, 0.f};
      vacc[mf][njl] = (f32x4){0.f, 0.f, 0.f, 0.f};
    }
  #pragma unroll
  for (int kk = 0; kk < 4; ++kk) {
    bf16x8 afh[3], afl[3];
    #pragma unroll
    for (int mf = 0; mf < 3; ++mf) {
      const float* pa = &f_lds[(mf * 16 + col) * 132 + kk * 32 + kg * 8];
      uint4 hi, lo;
      pack8(*(const float4*)pa, *(const float4*)(pa + 4), hi, lo);
      afh[mf] = *(bf16x8*)&hi; afl[mf] = *(bf16x8*)&lo;
    }
    #pragma unroll
    for (int njl = 0; njl < 2; ++njl) {
      const unsigned short* wbq = WB + (size_t)(tb_p + kk * 8 + nj0 + njl) * 1024 + lane * 8;
      bf16x8 qbh = *(const bf16x8*)wbq, qbl = *(const bf16x8*)(wbq + 512);
      #pragma unroll
      for (int mf = 0; mf < 3; ++mf) {
        qacc[mf][njl] = __builtin_amdgcn_mfma_f32_16x16x32_bf16(afh[mf], qbh, qacc[mf][njl], 0, 0, 0);
        qacc[mf][njl] = __builtin_amdgcn_mfma_f32_16x16x32_bf16(afh[mf], qbl, qacc[mf][njl], 0, 0, 0);
        qacc[mf][njl] = __builtin_amdgcn_mfma_f32_16x16x32_bf16(afl[mf], qbh, qacc[mf][njl], 0, 0, 0);
      }
      if (is_kv) {
        const unsigned short* wbv = WB + (size_t)(160 + kk * 8 + nj0 + njl) * 1024 + lane * 8;
        bf16x8 vbh = *(const bf16x8*)wbv, vbl = *(const bf16x8*)(wbv + 512);
        #pragma unroll
        for (int mf = 0; mf < 3; ++mf) {
          vacc[mf][njl] = __builtin_amdgcn_mfma_f32_16x16x32_bf16(afh[mf], vbh, vacc[mf][njl], 0, 0, 0);
          vacc[mf][njl] = __builtin_amdgcn_mfma_f32_16x16x32_bf16(afh[mf], vbl, vacc[mf][njl], 0, 0, 0);
          vacc[mf][njl] = __builtin_amdgcn_mfma_f32_16x16x32_bf16(afl[mf], vbh, vacc[mf][njl], 0, 0, 0);
        }
      }
    }
  }
  __syncthreads();

  #pragma unroll
  for (int njl = 0; njl < 2; ++njl) {
    #pragma unroll
    for (int i = 0; i < 4; ++i) {
      float ss = qacc[0][njl][i] * qacc[0][njl][i]
               + qacc[1][njl][i] * qacc[1][njl][i]
               + qacc[2][njl][i] * qacc[2][njl][i];
      ss += __shfl_xor(ss, 1, 16);
      ss += __shfl_xor(ss, 2, 16);
      ss += __shfl_xor(ss, 4, 16);
      ss += __shfl_xor(ss, 8, 16);
      float inv = ln_sc / (sqrtf(ss * (1.f / 16.f)) + EPSV);
      const int tl = kg * 4 + i;
      #pragma unroll
      for (int mf = 0; mf < 3; ++mf)
        stage[tl * 388 + mf * 128 + (nj0 + njl) * 16 + col] = qacc[mf][njl][i] * inv;
    }
  }
  __syncthreads();

  {
    const int f0 = lane >> 5;
    const int ddb = ((lane >> 4) & 1) * 8;
    const int row = lane & 15;
    #pragma unroll
    for (int h2 = 0; h2 < 2; ++h2) {
      const int hh = wv * 2 + h2;
      const int hbw = hh * BB + bsel;
      const size_t basew = (size_t)(hbw * 128 + (n0 >> 4)) * 1536;
      {
        const float* p0 = stage + row * 388 + f0 * 128 + hh * 16 + ddb;
        uint4 hi, lo;
        pack8(*(const float4*)p0, *(const float4*)(p0 + 4), hi, lo);
        *(uint4*)(FW + basew + lane * 8) = hi;
        *(uint4*)(FW + basew + 768 + lane * 8) = lo;
      }
      if (lane < 32) {
        const float* p1 = stage + row * 388 + 2 * 128 + hh * 16 + ddb;
        uint4 hi, lo;
        pack8(*(const float4*)p1, *(const float4*)(p1 + 4), hi, lo);
        *(uint4*)(FW + basew + 512 + lane * 8) = hi;
        *(uint4*)(FW + basew + 768 + 512 + lane * 8) = lo;
      }
    }
  }

  if (is_kv) {
    __syncthreads();
    #pragma unroll
    for (int njl = 0; njl < 2; ++njl)
      #pragma unroll
      for (int mf = 0; mf < 3; ++mf)
        #pragma unroll
        for (int i = 0; i < 4; ++i)
          stage[mf * 2112 + (kg * 4 + i) * 132 + (nj0 + njl) * 16 + col] = vacc[mf][njl][i];
    __syncthreads();

    const int s0 = (n0 >> 3) & 3;
    if (lane < 32) {
      const int seg = lane;
      const int tlb = (seg >> 4) * 8;
      const int dd = seg & 15;
      #pragma unroll
      for (int h2 = 0; h2 < 2; ++h2) {
        const int hh = wv * 2 + h2;
        const int hbw = hh * BB + bsel;
        #pragma unroll
        for (int f = 0; f < 3; ++f) {
          const size_t vbase = (size_t)((hbw * 64 + (n0 >> 5)) * 3 + f) * 1024;
          float vals[8];
          #pragma unroll
          for (int j = 0; j < 8; ++j)
            vals[j] = stage[f * 2112 + (tlb + j) * 132 + hh * 16 + dd];
          float4 a = {vals[0], vals[1], vals[2], vals[3]};
          float4 b = {vals[4], vals[5], vals[6], vals[7]};
          uint4 hi, lo;
          pack8(a, b, hi, lo);
          *(uint4*)(VW + vbase + (size_t)(s0 * 16 + seg) * 8) = hi;
          *(uint4*)(VW + vbase + 512 + (size_t)(s0 * 16 + seg) * 8) = lo;
        }
      }
    }
  }
}

// ---------------------------------------------------------------------------
// attention: MFMA flash, 4-way K-split, 32 q per wave. XCD-aware block
// swizzle: all blocks of an hb-pair land on one XCD (K/V set 1.6MB < 4MB L2).
// ---------------------------------------------------------------------------
#define THR 10.0f

__global__ __launch_bounds__(512, 4) void attn_kernel(
    const unsigned short* __restrict__ QW, const unsigned short* __restrict__ KW,
    const unsigned short* __restrict__ VW, float* __restrict__ Ob)
{
  const int lane = threadIdx.x & 63;
  const int w = threadIdx.x >> 6;
  const int qt = w & 1;
  const int kq = w >> 1;
  // XCD swizzle: fid round-robins over 8 XCDs; give XCD k hb {2k, 2k+1}.
  const int fid = blockIdx.y * 32 + blockIdx.x;
  const int xcd = fid & 7, slot = fid >> 3;
  const int hb = xcd * 2 + (slot >> 5);
  const int bx = slot & 31;
  const int tA = bx * 4 + qt * 2;
  const int q = lane & 15, g = lane >> 4;

  __shared__ unsigned short plds[8][2][1152];
  float* comb = (float*)plds;

  bf16x8 qh0[2], ql0[2], qh1[2], ql1[2];
  #pragma unroll
  for (int qs = 0; qs < 2; ++qs) {
    const size_t qbase = (size_t)(hb * 128 + tA + qs) * 1536;
    qh0[qs] = *(const bf16x8*)(QW + qbase + lane * 8);
    ql0[qs] = *(const bf16x8*)(QW + qbase + 768 + lane * 8);
    qh1[qs] = (bf16x8){0,0,0,0,0,0,0,0};
    ql1[qs] = (bf16x8){0,0,0,0,0,0,0,0};
    if (lane < 32) {
      qh1[qs] = *(const bf16x8*)(QW + qbase + 512 + lane * 8);
      ql1[qs] = *(const bf16x8*)(QW + qbase + 768 + 512 + lane * 8);
    }
  }

  f32x4 o[2][3];
  #pragma unroll
  for (int qs = 0; qs < 2; ++qs)
    #pragma unroll
    for (int f = 0; f < 3; ++f) o[qs][f] = (f32x4){0.f, 0.f, 0.f, 0.f};
  float m[2] = {-INFINITY, -INFINITY}, l[2] = {0.f, 0.f};

  for (int T = kq * 8; T < kq * 8 + 8; ++T) {
    f32x4 sc[2][4];
    __builtin_amdgcn_s_setprio(1);
    #pragma unroll
    for (int st = 0; st < 4; ++st) {
      const size_t kb = (size_t)(hb * 128 + T * 4 + st) * 1536;
      bf16x8 kh0 = *(const bf16x8*)(KW + kb + lane * 8);
      bf16x8 kl0 = *(const bf16x8*)(KW + kb + 768 + lane * 8);
      bf16x8 kh1 = *(const bf16x8*)(KW + kb + 512 + lane * 8);
      bf16x8 kl1 = *(const bf16x8*)(KW + kb + 768 + 512 + lane * 8);
      #pragma unroll
      for (int qs = 0; qs < 2; ++qs) {
        f32x4 a = {0.f, 0.f, 0.f, 0.f};
        a = __builtin_amdgcn_mfma_f32_16x16x32_bf16(kh0, qh0[qs], a, 0, 0, 0);
        a = __builtin_amdgcn_mfma_f32_16x16x32_bf16(kh0, ql0[qs], a, 0, 0, 0);
        a = __builtin_amdgcn_mfma_f32_16x16x32_bf16(kl0, qh0[qs], a, 0, 0, 0);
        a = __builtin_amdgcn_mfma_f32_16x16x32_bf16(kh1, qh1[qs], a, 0, 0, 0);
        a = __builtin_amdgcn_mfma_f32_16x16x32_bf16(kh1, ql1[qs], a, 0, 0, 0);
        a = __builtin_amdgcn_mfma_f32_16x16x32_bf16(kl1, qh1[qs], a, 0, 0, 0);
        sc[qs][st] = a;
      }
    }
    __builtin_amdgcn_s_setprio(0);

    #pragma unroll
    for (int qs = 0; qs < 2; ++qs) {
      float tm = sc[qs][0][0];
      #pragma unroll
      for (int st = 0; st < 4; ++st)
        #pragma unroll
        for (int r = 0; r < 4; ++r) tm = fmaxf(tm, sc[qs][st][r]);
      tm = fmaxf(tm, __shfl_xor(tm, 16));
      tm = fmaxf(tm, __shfl_xor(tm, 32));
      if (__any(tm > m[qs] + THR)) {
        float mnew = fmaxf(m[qs], tm);
        float scl = __builtin_amdgcn_exp2f(m[qs] - mnew);
        l[qs] *= scl;
        #pragma unroll
        for (int f = 0; f < 3; ++f) {
          o[qs][f][0] *= scl; o[qs][f][1] *= scl;
          o[qs][f][2] *= scl; o[qs][f][3] *= scl;
        }
        m[qs] = mnew;
      }
      float lp = 0.f;
      #pragma unroll
      for (int st = 0; st < 4; ++st) {
        float p0 = __builtin_amdgcn_exp2f(sc[qs][st][0] - m[qs]);
        float p1 = __builtin_amdgcn_exp2f(sc[qs][st][1] - m[qs]);
        float p2 = __builtin_amdgcn_exp2f(sc[qs][st][2] - m[qs]);
        float p3 = __builtin_amdgcn_exp2f(sc[qs][st][3] - m[qs]);
        lp += (p0 + p1) + (p2 + p3);
        uint2 uh = {cvt_pk_bf16(p0, p1), cvt_pk_bf16(p2, p3)};
        *(uint2*)&plds[w][qs][q * 72 + st * 16 + g * 4] = uh;
      }
      lp += __shfl_xor(lp, 16);
      lp += __shfl_xor(lp, 32);
      l[qs] += lp;
    }

    asm volatile("s_waitcnt lgkmcnt(0)" ::: "memory");

    __builtin_amdgcn_s_setprio(1);
    #pragma unroll
    for (int c = 0; c < 2; ++c) {
      const int kc = T * 2 + c;
      bf16x8 pb[2];
      #pragma unroll
      for (int qs = 0; qs < 2; ++qs)
        pb[qs] = *(const bf16x8*)&plds[w][qs][q * 72 + c * 32 + g * 8];
      #pragma unroll
      for (int f = 0; f < 3; ++f) {
        const size_t vb = (size_t)((hb * 64 + kc) * 3 + f) * 1024;
        bf16x8 vh = *(const bf16x8*)(VW + vb + lane * 8);
        bf16x8 vl = *(const bf16x8*)(VW + vb + 512 + lane * 8);
        #pragma unroll
        for (int qs = 0; qs < 2; ++qs) {
          o[qs][f] = __builtin_amdgcn_mfma_f32_16x16x32_bf16(vh, pb[qs], o[qs][f], 0, 0, 0);
          o[qs][f] = __builtin_amdgcn_mfma_f32_16x16x32_bf16(vl, pb[qs], o[qs][f], 0, 0, 0);
        }
      }
    }
    __builtin_amdgcn_s_setprio(0);
  }

  #define SLOT(qt_, qs_, r_) (comb + ((((qt_) * 2 + (qs_)) * 2 + (r_)) * 64 + lane) * 14)
  __syncthreads();
  if (kq & 1) {
    #pragma unroll
    for (int qs = 0; qs < 2; ++qs) {
      float* cb = SLOT(qt, qs, kq >> 1);
      #pragma unroll
      for (int f = 0; f < 3; ++f)
        #pragma unroll
        for (int r = 0; r < 4; ++r) cb[f * 4 + r] = o[qs][f][r];
      cb[12] = m[qs]; cb[13] = l[qs];
    }
  }
  __syncthreads();
  if (!(kq & 1)) {
    #pragma unroll
    for (int qs = 0; qs < 2; ++qs) {
      const float* cb = SLOT(qt, qs, kq >> 1);
      float m1 = cb[12], l1 = cb[13];
      float mn = fmaxf(m[qs], m1);
      float s0 = __builtin_amdgcn_exp2f(m[qs] - mn);
      float s1 = __builtin_amdgcn_exp2f(m1 - mn);
      l[qs] = l[qs] * s0 + l1 * s1;
      #pragma unroll
      for (int f = 0; f < 3; ++f)
        #pragma unroll
        for (int r = 0; r < 4; ++r)
          o[qs][f][r] = o[qs][f][r] * s0 + cb[f * 4 + r] * s1;
      m[qs] = mn;
    }
  }
  __syncthreads();
  if (kq == 2) {
    #pragma unroll
    for (int qs = 0; qs < 2; ++qs) {
      float* cb = SLOT(qt, qs, 1);
      #pragma unroll
      for (int f = 0; f < 3; ++f)
        #pragma unroll
        for (int r = 0; r < 4; ++r) cb[f * 4 + r] = o[qs][f][r];
      cb[12] = m[qs]; cb[13] = l[qs];
    }
  }
  __syncthreads();
  if (kq == 0) {
    const int h_ = hb >> 1, b_ = hb & 1;
    #pragma unroll
    for (int qs = 0; qs < 2; ++qs) {
      const float* cb = SLOT(qt, qs, 1);
      float m1 = cb[12], l1 = cb[13];
      float mn = fmaxf(m[qs], m1);
      float s0 = __builtin_amdgcn_exp2f(m[qs] - mn);
      float s1 = __builtin_amdgcn_exp2f(m1 - mn);
      float invl = 1.f / (l[qs] * s0 + l1 * s1);
      const int n = (tA + qs) * 16 + q;
      #pragma unroll
      for (int f = 0; f < 3; ++f) {
        float4 st4 = {(o[qs][f][0] * s0 + cb[f * 4 + 0] * s1) * invl,
                      (o[qs][f][1] * s0 + cb[f * 4 + 1] * s1) * invl,
                      (o[qs][f][2] * s0 + cb[f * 4 + 2] * s1) * invl,
                      (o[qs][f][3] * s0 + cb[f * 4 + 3] * s1) * invl};
        *(float4*)&Ob[(((size_t)(b_ * NN + n)) * 3 + f) * 128 + h_ * 16 + g * 4] = st4;
      }
    }
  }
  #undef SLOT
}

// ---------------------------------------------------------------------------
// out (MFMA): ev_nonlin(resi @ w_out). 16 tokens / 256 threads. (r17 good)
// ---------------------------------------------------------------------------
__global__ __launch_bounds__(256) void out_kernel(
    const float* __restrict__ Ob,
    const float* __restrict__ b1, const float* __restrict__ b2,
    const unsigned short* __restrict__ WB,
    float* __restrict__ out)
{
  const int t0 = blockIdx.x * TBP;
  const int tid = threadIdx.x;
  const int wv = tid >> 6, lane = tid & 63;
  const int col = lane & 15, kg = lane >> 4;
  const int nj0 = wv * 2;

  __shared__ __align__(16) char smem[38144];
  float* rs_lds   = (float*)smem;
  float* norm_lds = (float*)(smem + 25344);
  float* h_lds    = (float*)(smem + 33792);
  float* stage    = (float*)smem;

  {
    const float4* src = (const float4*)(Ob + (size_t)t0 * 384);
    #pragma unroll
    for (int i = 0; i < 6; ++i) {
      int idx = tid + i * 256;
      int tok = idx / 96, rem = idx % 96;
      int f = rem / 32, c4 = rem % 32;
      *(float4*)&rs_lds[f * 2112 + tok * 132 + c4 * 4] = src[idx];
    }
  }
  __syncthreads();

  f32x4 pacc[3][2];
  #pragma unroll
  for (int mf = 0; mf < 3; ++mf)
    #pragma unroll
    for (int njl = 0; njl < 2; ++njl) pacc[mf][njl] = (f32x4){0.f, 0.f, 0.f, 0.f};
  #pragma unroll
  for (int kk = 0; kk < 4; ++kk) {
    bf16x8 ah[3], al[3];
    #pragma unroll
    for (int mf = 0; mf < 3; ++mf) {
      const float* pa = &rs_lds[mf * 2112 + col * 132 + kk * 32 + kg * 8];
      uint4 hi, lo;
      pack8(*(const float4*)pa, *(const float4*)(pa + 4), hi, lo);
      ah[mf] = *(bf16x8*)&hi; al[mf] = *(bf16x8*)&lo;
    }
    #pragma unroll
    for (int njl = 0; njl < 2; ++njl) {
      const unsigned short* wb = WB + (size_t)(192 + kk * 8 + nj0 + njl) * 1024 + lane * 8;
      bf16x8 bh = *(const bf16x8*)wb, bl = *(const bf16x8*)(wb + 512);
      #pragma unroll
      for (int mf = 0; mf < 3; ++mf) {
        pacc[mf][njl] = __builtin_amdgcn_mfma_f32_16x16x32_bf16(ah[mf], bh, pacc[mf][njl], 0, 0, 0);
        pacc[mf][njl] = __builtin_amdgcn_mfma_f32_16x16x32_bf16(ah[mf], bl, pacc[mf][njl], 0, 0, 0);
        pacc[mf][njl] = __builtin_amdgcn_mfma_f32_16x16x32_bf16(al[mf], bh, pacc[mf][njl], 0, 0, 0);
      }
    }
  }

  f32x4 np4[2]; int zm = 0;
  #pragma unroll
  for (int njl = 0; njl < 2; ++njl) {
    f32x4 ss = pacc[0][njl] * pacc[0][njl] + pacc[1][njl] * pacc[1][njl] + pacc[2][njl] * pacc[2][njl];
    #pragma unroll
    for (int i = 0; i < 4; ++i) {
      float nn = sqrtf(ss[i]);
      if (nn <= EPSV) zm |= 1 << (njl * 4 + i);
      np4[njl][i] = nn + EPSV;
      norm_lds[(kg * 4 + i) * 132 + (nj0 + njl) * 16 + col] = np4[njl][i];
    }
  }
  __syncthreads();

  {
    f32x4 hacc = {0.f, 0.f, 0.f, 0.f};
    #pragma unroll
    for (int kk = 0; kk < 4; ++kk) {
      const float* pa = &norm_lds[col * 132 + kk * 32 + kg * 8];
      uint4 hi, lo;
      pack8(*(const float4*)pa, *(const float4*)(pa + 4), hi, lo);
      bf16x8 ah = *(bf16x8*)&hi, al = *(bf16x8*)&lo;
      const unsigned short* wb = WB + (size_t)(224 + kk * 4 + wv) * 1024 + lane * 8;
      bf16x8 bh = *(const bf16x8*)wb, bl = *(const bf16x8*)(wb + 512);
      hacc = __builtin_amdgcn_mfma_f32_16x16x32_bf16(ah, bh, hacc, 0, 0, 0);
      hacc = __builtin_amdgcn_mfma_f32_16x16x32_bf16(ah, bl, hacc, 0, 0, 0);
      hacc = __builtin_amdgcn_mfma_f32_16x16x32_bf16(al, bh, hacc, 0, 0, 0);
    }
    float b1v = b1[wv * 16 + col];
    #pragma unroll
    for (int i = 0; i < 4; ++i)
      h_lds[(kg * 4 + i) * 68 + wv * 16 + col] = leaky(hacc[i] + b1v);
  }
  __syncthreads();

  {
    f32x4 bna[2] = {{0.f, 0.f, 0.f, 0.f}, {0.f, 0.f, 0.f, 0.f}};
    #pragma unroll
    for (int kk = 0; kk < 2; ++kk) {
      const float* pa = &h_lds[col * 68 + kk * 32 + kg * 8];
      uint4 hi, lo;
      pack8(*(const float4*)pa, *(const float4*)(pa + 4), hi, lo);
      bf16x8 ah = *(bf16x8*)&hi, al = *(bf16x8*)&lo;
      #pragma unroll
      for (int njl = 0; njl < 2; ++njl) {
        const unsigned short* wb = WB + (size_t)(240 + kk * 8 + nj0 + njl) * 1024 + lane * 8;
        bf16x8 bh = *(const bf16x8*)wb, bl = *(const bf16x8*)(wb + 512);
        bna[njl] = __builtin_amdgcn_mfma_f32_16x16x32_bf16(ah, bh, bna[njl], 0, 0, 0);
        bna[njl] = __builtin_amdgcn_mfma_f32_16x16x32_bf16(ah, bl, bna[njl], 0, 0, 0);
        bna[njl] = __builtin_amdgcn_mfma_f32_16x16x32_bf16(al, bh, bna[njl], 0, 0, 0);
      }
    }
    __syncthreads();
    #pragma unroll
    for (int njl = 0; njl < 2; ++njl) {
      float b2v = b2[(nj0 + njl) * 16 + col];
      #pragma unroll
      for (int i = 0; i < 4; ++i) {
        float r = (zm >> (njl * 4 + i)) & 1 ? 1.f
                 : (bna[njl][i] + b2v + np4[njl][i]) / np4[njl][i];
        #pragma unroll
        for (int mf = 0; mf < 3; ++mf)
          stage[(kg * 4 + i) * 388 + mf * 128 + (nj0 + njl) * 16 + col] = pacc[mf][njl][i] * r;
      }
    }
  }
  __syncthreads();

  {
    float4* dst = (float4*)(out + (size_t)t0 * 384);
    #pragma unroll
    for (int i = 0; i < 6; ++i) {
      int idx = tid + i * 256;
      int tok = idx / 96, rem = idx % 96;
      dst[idx] = *(const float4*)&stage[tok * 388 + rem * 4];
    }
  }
}

// ---------------------------------------------------------------------------
extern "C" void kernel_launch(void* const* d_in, const int* in_sizes, int n_in,
                              void* d_out, int out_size, void* d_ws, size_t ws_size,
                              hipStream_t stream) {
  const float* qfts   = (const float*)d_in[0];
  const float* kvfts  = (const float*)d_in[1];
  const float* w_q_in = (const float*)d_in[2];
  const float* q_w1   = (const float*)d_in[3];
  const float* q_b1   = (const float*)d_in[4];
  const float* q_w2   = (const float*)d_in[5];
  const float* q_b2   = (const float*)d_in[6];
  const float* w_kv_in= (const float*)d_in[7];
  const float* kv_w1  = (const float*)d_in[8];
  const float* kv_b1  = (const float*)d_in[9];
  const float* kv_w2  = (const float*)d_in[10];
  const float* kv_b2  = (const float*)d_in[11];
  const float* w_q    = (const float*)d_in[12];
  const float* w_k    = (const float*)d_in[13];
  const float* w_v    = (const float*)d_in[14];
  const float* w_out  = (const float*)d_in[15];
  const float* o_w1   = (const float*)d_in[16];
  const float* o_b1   = (const float*)d_in[17];
  const float* o_w2   = (const float*)d_in[18];
  const float* o_b2   = (const float*)d_in[19];

  unsigned short* QW = (unsigned short*)d_ws;
  unsigned short* KW = QW + 3145728;
  unsigned short* VW = KW + 3145728;
  float* Obuf = (float*)(VW + 3145728);
  unsigned short* WB = (unsigned short*)(Obuf + 1572864);

  wconv_kernel<<<256, 64, 0, stream>>>(w_q_in, q_w1, q_w2, w_kv_in, kv_w1, kv_w2,
                                       w_q, w_k, w_v, w_out, o_w1, o_w2, WB);
  dim3 pg(BB * NN / TBP, 2);
  pre_kernel<<<pg, 256, 0, stream>>>(qfts, kvfts, q_b1, q_b2, kv_b1, kv_b2,
                                     WB, QW, KW, VW);
  dim3 ag(32, 16);
  attn_kernel<<<ag, 512, 0, stream>>>(QW, KW, VW, Obuf);
  out_kernel<<<BB * NN / TBP, 256, 0, stream>>>(Obuf, o_b1, o_b2, WB, (float*)d_out);
}